// Round 8
// baseline (1395.812 us; speedup 1.0000x reference)
//
#include <hip/hip_runtime.h>
#include <hip/hip_bf16.h>
#include <math.h>

// Problem constants: T=2048, B=4096, IN_S=1, H=20, OUT_S=1
#define TT 2048
#define BB 4096
#define HH 20

typedef float v2f __attribute__((ext_vector_type(2)));

#define L2E 1.4426950408889634f  // log2(e)

__device__ __forceinline__ float rcp_fast(float x)  { return __builtin_amdgcn_rcpf(x); }
__device__ __forceinline__ float exp2_fast(float x) { return __builtin_amdgcn_exp2f(x); }

// Backend selects v_pk_fma_f32 — no inline-asm pinning (R5 lesson).
__device__ __forceinline__ v2f pk_fma(v2f a, v2f b, v2f c) {
    return __builtin_elementwise_fma(a, b, c);
}

// One wave per block; TWO PHASE-SHIFTED chains (A,B) of 3 batches each.
// Lanes [0..19],[20..39],[40..59] = 3 groups; lane -> (group, unit j).
// Weights shared between chains. Phase shift: chain A's LDS write->read
// round-trip is in flight while chain B's gates+activations issue, and vice
// versa. R7 LESSON: the write->read cross-lane visibility REQUIRES an
// explicit s_waitcnt lgkmcnt(0) (or compiler-visible aliasing so the
// compiler inserts one). R7's __restrict__ LDS pointers suppressed it ->
// stale h. Here: explicit waitcnt between each chain's write and read-back.
__global__ __launch_bounds__(64, 1) void lstm_fused_kernel(
    const float* __restrict__ u,      // [T, B, 1]
    const float* __restrict__ W_ih,   // [4H, 1]
    const float* __restrict__ W_hh,   // [4H, H]
    const float* __restrict__ W_out,  // [1, H]
    float* __restrict__ y)            // [T, B, 1]
{
    __shared__ __align__(16) float hbufA[4][HH];
    __shared__ __align__(16) float hbufB[4][HH];

    const int lane  = threadIdx.x;
    const int group = lane / HH;          // 0..3 (3 == idle)
    const int j     = lane - group * HH;  // 0..19
    const int bA = blockIdx.x * 6 + group;
    const int bB = blockIdx.x * 6 + 3 + group;
    const bool actA = (group < 3) && (bA < BB);
    const bool actB = (group < 3) && (bB < BB);
    const int lbA = actA ? bA : 0;
    const int lbB = actB ? bB : 0;

    // ---- Weights (shared by both chains), packed along k, exp2-prescaled:
    // i,f,o rows * -log2(e); g row * 2*log2(e).
    v2f wg[4][HH / 2];
    const float gsc[4] = {-L2E, -L2E, 2.0f * L2E, -L2E};
    #pragma unroll
    for (int g = 0; g < 4; ++g) {
        #pragma unroll
        for (int m = 0; m < HH / 2; ++m) {
            wg[g][m].x = gsc[g] * W_hh[(g * HH + j) * HH + 2 * m];
            wg[g][m].y = gsc[g] * W_hh[(g * HH + j) * HH + 2 * m + 1];
        }
    }
    float wih[4];
    #pragma unroll
    for (int g = 0; g < 4; ++g) wih[g] = gsc[g] * W_ih[g * HH + j];
    v2f wo2[HH / 2];
    #pragma unroll
    for (int m = 0; m < HH / 2; ++m) { wo2[m].x = W_out[2 * m]; wo2[m].y = W_out[2 * m + 1]; }

    // ---- Per-chain state: h_{t-1} pairs live in REGISTERS; LDS is only the
    // broadcast medium (write h_t; read back while the other chain computes).
    v2f hA[10], hB[10];
    #pragma unroll
    for (int m = 0; m < 10; ++m) { hA[m] = (v2f){0.f, 0.f}; hB[m] = (v2f){0.f, 0.f}; }
    float cA = 0.0f, cB = 0.0f;

    const float* __restrict__ upA = u + lbA;
    const float* __restrict__ upB = u + lbB;
    float* __restrict__ ypA = y + lbA;
    float* __restrict__ ypB = y + lbB;

    float uA[4], uB[4];
    #pragma unroll
    for (int k = 0; k < 4; ++k) {
        uA[k] = upA[(size_t)k * BB];
        uB[k] = upB[(size_t)k * BB];
    }

    // NOTE: no __restrict__ on LDS pointers — compiler must see may-alias.
    const v2f* hsA = (const v2f*)(&hbufA[group][0]);
    const v2f* hsB = (const v2f*)(&hbufB[group][0]);

    // One chain's step. Gates use register h (= h_{t-1}); write h_t; waitcnt
    // so the write is visible; issue read-back of h_t (consumed NEXT step for
    // this chain, so its latency is covered by the OTHER chain's section).
    auto chain_step = [&](v2f (&h)[10], float& c, float uv,
                          float (&hrow)[HH], const v2f* hsrc,
                          float& yout) {
        v2f a0 = {0.f, 0.f}, a1 = {0.f, 0.f}, a2 = {0.f, 0.f}, a3 = {0.f, 0.f};
        v2f ay = {0.f, 0.f};
        #pragma unroll
        for (int m = 0; m < 10; ++m) {
            v2f hp = h[m];
            a0 = pk_fma(wg[0][m], hp, a0);
            a1 = pk_fma(wg[1][m], hp, a1);
            a2 = pk_fma(wg[2][m], hp, a2);
            a3 = pk_fma(wg[3][m], hp, a3);
            ay = pk_fma(wo2[m],   hp, ay);
        }
        const float g0 = fmaf(uv, wih[0], a0.x + a0.y);
        const float g1 = fmaf(uv, wih[1], a1.x + a1.y);
        const float g2 = fmaf(uv, wih[2], a2.x + a2.y);
        const float g3 = fmaf(uv, wih[3], a3.x + a3.y);
        yout = ay.x + ay.y;  // y_{t-1} (one-step-delayed output)

        const float ig = rcp_fast(1.0f + exp2_fast(g0));
        const float fg = rcp_fast(1.0f + exp2_fast(g1));
        const float og = rcp_fast(1.0f + exp2_fast(g3));
        const float eg = exp2_fast(-fabsf(g2));
        const float tg = (1.0f - eg) * rcp_fast(1.0f + eg);
        const float gg = copysignf(tg, g2);

        c = fmaf(fg, c, ig * gg);
        const float ec = exp2_fast(-2.0f * L2E * fabsf(c));
        const float tc = (1.0f - ec) * rcp_fast(1.0f + ec);
        const float hv = og * copysignf(tc, c);

        hrow[j] = hv;                                        // ds_write h_t
        asm volatile("s_waitcnt lgkmcnt(0)" ::: "memory");   // REQUIRED: make
        // the write visible before the cross-lane read (R7 failure mode).
        #pragma unroll
        for (int m = 0; m < 10; ++m) h[m] = hsrc[m];         // ds_read h_t
        asm volatile("" ::: "memory");                       // pin read placement
    };

    for (int t4 = 0; t4 < TT; t4 += 4) {
        const int tn = (t4 + 4 < TT) ? (t4 + 4) : t4;
        float uAn[4], uBn[4];
        #pragma unroll
        for (int k = 0; k < 4; ++k) {
            uAn[k] = upA[(size_t)(tn + k) * BB];
            uBn[k] = upB[(size_t)(tn + k) * BB];
        }

        float yA4[4], yB4[4];

        #pragma unroll
        for (int tt = 0; tt < 4; ++tt) {
            chain_step(hA, cA, uA[tt], hbufA[group], hsA, yA4[tt]);  // A covers B's read
            chain_step(hB, cB, uB[tt], hbufB[group], hsB, yB4[tt]);  // B covers A's read
        }

        if (j == 0) {
            #pragma unroll
            for (int k = 0; k < 4; ++k) {
                const int idx = t4 - 1 + k;
                if (idx >= 0) {
                    if (actA) ypA[(size_t)idx * BB] = yA4[k];
                    if (actB) ypB[(size_t)idx * BB] = yB4[k];
                }
            }
        }

        #pragma unroll
        for (int k = 0; k < 4; ++k) { uA[k] = uAn[k]; uB[k] = uBn[k]; }
    }

    // Epilogue: y_{T-1} for both chains from the final h (in registers).
    {
        v2f ayA = {0.f, 0.f}, ayB = {0.f, 0.f};
        #pragma unroll
        for (int m = 0; m < 10; ++m) {
            ayA = pk_fma(wo2[m], hA[m], ayA);
            ayB = pk_fma(wo2[m], hB[m], ayB);
        }
        if (j == 0) {
            if (actA) ypA[(size_t)(TT - 1) * BB] = ayA.x + ayA.y;
            if (actB) ypB[(size_t)(TT - 1) * BB] = ayB.x + ayB.y;
        }
    }
}

extern "C" void kernel_launch(void* const* d_in, const int* in_sizes, int n_in,
                              void* d_out, int out_size, void* d_ws, size_t ws_size,
                              hipStream_t stream) {
    const float* u     = (const float*)d_in[0];   // [2048, 4096, 1]
    const float* W_ih  = (const float*)d_in[1];   // [80, 1]
    const float* W_hh  = (const float*)d_in[2];   // [80, 20]
    const float* W_out = (const float*)d_in[3];   // [1, 20]
    float* y = (float*)d_out;                      // [2048, 4096, 1]

    const int blocks = (BB + 5) / 6;  // 6 batches (2 chains x 3) per wave -> 683
    lstm_fused_kernel<<<dim3(blocks), dim3(64), 0, stream>>>(u, W_ih, W_hh, W_out, y);
}

// Round 9
// 967.662 us; speedup vs baseline: 1.4425x; 1.4425x over previous
//
#include <hip/hip_runtime.h>
#include <hip/hip_bf16.h>
#include <math.h>

// Problem constants: T=2048, B=4096, IN_S=1, H=20, OUT_S=1
#define TT 2048
#define BB 4096
#define HH 20

typedef float v2f __attribute__((ext_vector_type(2)));

#define L2E 1.4426950408889634f  // log2(e)

__device__ __forceinline__ float rcp_fast(float x)  { return __builtin_amdgcn_rcpf(x); }
__device__ __forceinline__ float exp2_fast(float x) { return __builtin_amdgcn_exp2f(x); }

// Backend selects v_pk_fma_f32 — no inline-asm pinning (R5 lesson).
__device__ __forceinline__ v2f pk_fma(v2f a, v2f b, v2f c) {
    return __builtin_elementwise_fma(a, b, c);
}

// One wave per block, TWO batches per wave (lanes [0..19],[20..39]); lanes
// 40..63 idle. 4096/2 = 2048 blocks = EXACTLY 2 waves per SIMD chip-wide.
// R4/R8 lesson: the ~600-cyc per-step serial stall (LDS write-visibility +
// transcendental chains) is hidden by ANOTHER RESIDENT WAVE, not by
// intra-wave ILP — the HW wave scheduler switches for free; the compiler
// won't interleave across waitcnt boundaries. Ladder: 0.67 w/SIMD -> 1400us,
// 1.33 -> 984us; this tries 2.0. Wave-issue/step is unchanged by idle lanes.
__global__ __launch_bounds__(64, 2) void lstm_fused_kernel(
    const float* __restrict__ u,      // [T, B, 1]
    const float* __restrict__ W_ih,   // [4H, 1]
    const float* __restrict__ W_hh,   // [4H, H]
    const float* __restrict__ W_out,  // [1, H]
    float* __restrict__ y)            // [T, B, 1]
{
    // Single buffer. Compiler SEES the aliasing between write and reads ->
    // inserts the lgkmcnt wait itself (R6-verified correct; R7 showed
    // __restrict__ LDS pointers suppress it -> stale h).
    __shared__ __align__(16) float hbuf[4][HH];

    const int lane  = threadIdx.x;
    const int group = lane / HH;          // 0..3 (2,3 == idle)
    const int j     = lane - group * HH;  // 0..19
    const int b_real = blockIdx.x * 2 + group;
    const bool active = (group < 2) && (b_real < BB);
    const int b = active ? b_real : 0;

    // h_{-1} = 0 (all groups incl. idle regions).
    for (int i = lane; i < 4 * HH; i += 64) ((float*)hbuf)[i] = 0.0f;
    asm volatile("" ::: "memory");

    // ---- Weights in registers, packed along k: wg[g][m] = (w[2m], w[2m+1]).
    // Pre-scaled into exp2 domain: i,f,o rows * -log2(e); g row * 2*log2(e).
    v2f wg[4][HH / 2];
    const float gsc[4] = {-L2E, -L2E, 2.0f * L2E, -L2E};
    #pragma unroll
    for (int g = 0; g < 4; ++g) {
        #pragma unroll
        for (int m = 0; m < HH / 2; ++m) {
            wg[g][m].x = gsc[g] * W_hh[(g * HH + j) * HH + 2 * m];
            wg[g][m].y = gsc[g] * W_hh[(g * HH + j) * HH + 2 * m + 1];
        }
    }
    float wih[4];
    #pragma unroll
    for (int g = 0; g < 4; ++g) wih[g] = gsc[g] * W_ih[g * HH + j];
    v2f wo2[HH / 2];
    #pragma unroll
    for (int m = 0; m < HH / 2; ++m) { wo2[m].x = W_out[2 * m]; wo2[m].y = W_out[2 * m + 1]; }

    float c = 0.0f;
    const float* __restrict__ up = u + b;
    float* __restrict__ yp = y + b;

    float u_cur[4];
    #pragma unroll
    for (int k = 0; k < 4; ++k) u_cur[k] = up[(size_t)k * BB];

    const v2f* hs = (const v2f*)(&hbuf[group][0]);  // no restrict: must alias

    for (int t4 = 0; t4 < TT; t4 += 4) {
        const int tn = (t4 + 4 < TT) ? (t4 + 4) : t4;
        float u_nxt[4];
        #pragma unroll
        for (int k = 0; k < 4; ++k) u_nxt[k] = up[(size_t)(tn + k) * BB];

        float y4[4];  // y4[tt] = y_{t4+tt-1} (y reads the h broadcast one step late)

        #pragma unroll
        for (int tt = 0; tt < 4; ++tt) {
            // ---- read h_{t-1} as 10 pairs (compiler merges to ds_read_b128) ----
            v2f h2[10];
            #pragma unroll
            for (int m = 0; m < 10; ++m) h2[m] = hs[m];

            const float uv = u_cur[tt];
            v2f a0 = {uv * wih[0], 0.0f};
            v2f a1 = {uv * wih[1], 0.0f};
            v2f a2 = {uv * wih[2], 0.0f};
            v2f a3 = {uv * wih[3], 0.0f};
            v2f ay = {0.0f, 0.0f};

            // 50 v_pk_fma_f32; 5 accumulators round-robin -> dep spacing
            // 5 insts (10 cyc) > 4-cyc FMA latency.
            #pragma unroll
            for (int m = 0; m < 10; ++m) {
                v2f hp = h2[m];
                a0 = pk_fma(wg[0][m], hp, a0);
                a1 = pk_fma(wg[1][m], hp, a1);
                a2 = pk_fma(wg[2][m], hp, a2);
                a3 = pk_fma(wg[3][m], hp, a3);
                ay = pk_fma(wo2[m],   hp, ay);
            }
            const float g0 = a0.x + a0.y;  // exp2-domain pre-activations
            const float g1 = a1.x + a1.y;
            const float g2 = a2.x + a2.y;
            const float g3 = a3.x + a3.y;
            y4[tt] = ay.x + ay.y;          // = y_{t-1}

            // ---- activations (exp2 domain) ----
            const float ig = rcp_fast(1.0f + exp2_fast(g0));
            const float fg = rcp_fast(1.0f + exp2_fast(g1));
            const float og = rcp_fast(1.0f + exp2_fast(g3));
            const float eg = exp2_fast(-fabsf(g2));        // e^{-2|x_g|}
            const float tg = (1.0f - eg) * rcp_fast(1.0f + eg);
            const float gg = copysignf(tg, g2);

            c = fmaf(fg, c, ig * gg);
            const float ec = exp2_fast(-2.0f * L2E * fabsf(c));
            const float tc = (1.0f - ec) * rcp_fast(1.0f + ec);
            const float h  = og * copysignf(tc, c);

            // ---- broadcast h_t (compiler inserts the lgkmcnt wait: it sees
            // the write/read aliasing) ----
            hbuf[group][j] = h;
            asm volatile("" ::: "memory");
        }

        if (active && j == 0) {
            #pragma unroll
            for (int k = 0; k < 4; ++k) {
                const int idx = t4 - 1 + k;
                if (idx >= 0) yp[(size_t)idx * BB] = y4[k];
            }
        }

        #pragma unroll
        for (int k = 0; k < 4; ++k) u_cur[k] = u_nxt[k];
    }

    // Epilogue: y_{T-1} from the final h broadcast.
    {
        v2f ay = {0.0f, 0.0f};
        #pragma unroll
        for (int m = 0; m < 10; ++m) ay = pk_fma(wo2[m], hs[m], ay);
        if (active && j == 0) yp[(size_t)(TT - 1) * BB] = ay.x + ay.y;
    }
}

extern "C" void kernel_launch(void* const* d_in, const int* in_sizes, int n_in,
                              void* d_out, int out_size, void* d_ws, size_t ws_size,
                              hipStream_t stream) {
    const float* u     = (const float*)d_in[0];   // [2048, 4096, 1]
    const float* W_ih  = (const float*)d_in[1];   // [80, 1]
    const float* W_hh  = (const float*)d_in[2];   // [80, 20]
    const float* W_out = (const float*)d_in[3];   // [1, 20]
    float* y = (float*)d_out;                      // [2048, 4096, 1]

    const int blocks = BB / 2;  // 2 batches per single-wave block -> 2048 = 2 waves/SIMD
    lstm_fused_kernel<<<dim3(blocks), dim3(64), 0, stream>>>(u, W_ih, W_hh, W_out, y);
}